// Round 1
// baseline (482.708 us; speedup 1.0000x reference)
//
#include <hip/hip_runtime.h>

// Problem constants (from reference setup_inputs)
constexpr int B = 2, C = 16, D = 80, H = 96, W = 96;
constexpr int S  = D * H * W;        // 737280 spatial per batch
constexpr int N  = B * C * S;        // 23592960 elems per tensor
// Padded pooled layout: halo of 3 on d/h; w gets 4 left (alignment) + 12 right
constexpr int DP = D + 6;            // 86
constexpr int HP = H + 6;            // 102
constexpr int WP = 112;              // 4 + 96 + 12, multiple of 4 for float4 rows
constexpr int PP = DP * HP * WP;     // 982464 per channel per batch

// Workspace float offsets (all multiples of 4 -> float4 aligned)
constexpr int OFF_FMAX = 0;
constexpr int OFF_FAVG = B * PP;
constexpr int OFF_MMAX = 2 * B * PP;
constexpr int OFF_MAVG = 3 * B * PP;
constexpr int OFF_GF   = 4 * B * PP;
constexpr int OFF_GM   = OFF_GF + B * S;
// Total ws need: (OFF_GM + B*S)*4 = 43,235,328 bytes

__device__ __forceinline__ float sigmoidf_(float x) {
    return 1.0f / (1.0f + __expf(-x));
}

// ---------------------------------------------------------------------------
// Kernel 1: channel max/mean pool of fix and move into zero-padded planar
// layout. One thread per PADDED float4 slot; halo lanes write zeros (no
// separate memset dispatch). Interior lanes (75%) do the 16-channel pool.
// 1919 blocks x 256 -> 5.6 waves/SIMD: enough MLP for streaming.
// ---------------------------------------------------------------------------
__global__ __launch_bounds__(256) void pool_pad_kernel(
    const float* __restrict__ fix, const float* __restrict__ mov,
    float* __restrict__ ws)
{
    int i = blockIdx.x * 256 + threadIdx.x;        // over B*PP/4 padded float4s
    if (i >= B * PP / 4) return;

    int wp4 = i % (WP / 4);                         // 0..27
    int t   = i / (WP / 4);
    int hp  = t % HP;  t /= HP;
    int dp  = t % DP;
    int b   = t / DP;

    float4* ws4 = (float4*)ws;
    bool interior = (dp >= 3) & (dp < 3 + D) & (hp >= 3) & (hp < 3 + H)
                  & (wp4 >= 1) & (wp4 < 25);

    if (!interior) {
        float4 z = make_float4(0.f, 0.f, 0.f, 0.f);
        ws4[0 * (B * PP / 4) + i] = z;
        ws4[1 * (B * PP / 4) + i] = z;
        ws4[2 * (B * PP / 4) + i] = z;
        ws4[3 * (B * PP / 4) + i] = z;
        return;
    }

    int d = dp - 3, h = hp - 3, w4 = wp4 - 1;
    const float4* f4 = (const float4*)fix;
    const float4* m4 = (const float4*)mov;
    int base = (b * C * S + (d * H + h) * W) / 4 + w4;   // channel 0 slot
    constexpr int cs = S / 4;                            // channel stride (f4)

    float4 v = f4[base];
    float4 fmx = v, fsm = v;
    #pragma unroll
    for (int c = 1; c < C; c++) {
        v = f4[base + c * cs];
        fmx.x = fmaxf(fmx.x, v.x); fmx.y = fmaxf(fmx.y, v.y);
        fmx.z = fmaxf(fmx.z, v.z); fmx.w = fmaxf(fmx.w, v.w);
        fsm.x += v.x; fsm.y += v.y; fsm.z += v.z; fsm.w += v.w;
    }
    v = m4[base];
    float4 mmx = v, msm = v;
    #pragma unroll
    for (int c = 1; c < C; c++) {
        v = m4[base + c * cs];
        mmx.x = fmaxf(mmx.x, v.x); mmx.y = fmaxf(mmx.y, v.y);
        mmx.z = fmaxf(mmx.z, v.z); mmx.w = fmaxf(mmx.w, v.w);
        msm.x += v.x; msm.y += v.y; msm.z += v.z; msm.w += v.w;
    }
    constexpr float inv = 1.0f / C;
    ws4[0 * (B * PP / 4) + i] = fmx;
    ws4[1 * (B * PP / 4) + i] = make_float4(fsm.x*inv, fsm.y*inv, fsm.z*inv, fsm.w*inv);
    ws4[2 * (B * PP / 4) + i] = mmx;
    ws4[3 * (B * PP / 4) + i] = make_float4(msm.x*inv, msm.y*inv, msm.z*inv, msm.w*inv);
}

// ---------------------------------------------------------------------------
// Kernel 2: 7x7x7 conv over the 2 pooled channels + sigmoid -> gate arrays.
// Block (8,8,4) = 256 thr: 2x4 (h,w) register tile per thread at one d
// (halved from 4x4 to double occupancy: 1440 blocks -> 5760 waves =
// 5.6/SIMD, vs 2.8/SIMD before; dependent 7-deep fmac chains + L1 load
// latency need the extra waves to keep VALU issue full).
// Grid (3,6,160/2): z = tensor*40 + b*20 + dblk.
// Weights read DIRECTLY from global with wave-uniform indices -> compiler
// scalarizes to s_load; FMAs take the weight as the SGPR operand (no LDS).
// ---------------------------------------------------------------------------
__global__ __launch_bounds__(256) void conv_gate_kernel(
    const float* __restrict__ ws_in,
    const float* __restrict__ w_f2m, const float* __restrict__ w_m2f,
    float* __restrict__ ws_out)
{
    int z      = blockIdx.z;
    int tensor = z / (B * (D / 4));      // 0 = fix gate, 1 = move gate
    int zz     = z % (B * (D / 4));
    int b      = zz / (D / 4);
    int dblk   = zz % (D / 4);

    const float* wsrc = tensor ? w_m2f : w_f2m;
    const float* pmax = ws_in + (tensor ? OFF_MMAX : OFF_FMAX) + b * PP;
    const float* pavg = ws_in + (tensor ? OFF_MAVG : OFF_FAVG) + b * PP;
    float*       gate = ws_out + (tensor ? OFF_GM : OFF_GF) + b * S;

    int d  = dblk * 4 + threadIdx.z;
    int hb = blockIdx.y * 16 + threadIdx.y * 2;     // 2-row tile per thread
    int wb = blockIdx.x * 32 + threadIdx.x * 4;

    float acc[2][4];
    #pragma unroll
    for (int oh = 0; oh < 2; oh++)
        #pragma unroll
        for (int ow = 0; ow < 4; ow++) acc[oh][ow] = 0.0f;

    #pragma unroll 1
    for (int c = 0; c < 2; c++) {
        const float* src = c ? pavg : pmax;
        #pragma unroll 1
        for (int kd = 0; kd < 7; kd++) {
            const float* plane = src + (d + kd) * (HP * WP);
            float wt[49];                       // wave-uniform -> SGPRs
            #pragma unroll
            for (int j = 0; j < 49; j++) wt[j] = wsrc[(c * 7 + kd) * 49 + j];

            #pragma unroll
            for (int r = 0; r < 8; r++) {       // 2 output rows + 6 halo
                const float4* rp = (const float4*)(plane + (hb + r) * WP + wb);
                float4 a0 = rp[0], a1 = rp[1], a2 = rp[2];
                float row[12];
                row[0] = a0.x; row[1]  = a0.y; row[2]  = a0.z; row[3]  = a0.w;
                row[4] = a1.x; row[5]  = a1.y; row[6]  = a1.z; row[7]  = a1.w;
                row[8] = a2.x; row[9]  = a2.y; row[10] = a2.z; row[11] = a2.w;
                // padded row hb+r serves output rows oh with kh = r-oh in [0,7)
                #pragma unroll
                for (int oh = 0; oh < 2; oh++) {
                    int kh = r - oh;
                    if (kh >= 0 && kh < 7) {        // compile-time after unroll
                        #pragma unroll
                        for (int kw = 0; kw < 7; kw++) {
                            float wv = wt[kh * 7 + kw];
                            #pragma unroll
                            for (int ow = 0; ow < 4; ow++)
                                acc[oh][ow] = fmaf(row[ow + kw + 1], wv, acc[oh][ow]);
                        }
                    }
                }
            }
        }
    }

    #pragma unroll
    for (int oh = 0; oh < 2; oh++) {
        float4 o;
        o.x = sigmoidf_(acc[oh][0]);
        o.y = sigmoidf_(acc[oh][1]);
        o.z = sigmoidf_(acc[oh][2]);
        o.w = sigmoidf_(acc[oh][3]);
        *(float4*)(gate + (d * H + hb + oh) * W + wb) = o;
    }
}

// ---------------------------------------------------------------------------
// Kernel 3: elementwise cross-apply, full-occupancy streaming.
// fix_out = move*g_fix + fix ; move_out = fix*g_move + move.
// One thread per float4 of one tensor; writes both outputs. 23040 blocks.
// ---------------------------------------------------------------------------
__global__ __launch_bounds__(256) void apply_kernel(
    const float* __restrict__ fix, const float* __restrict__ mov,
    const float* __restrict__ ws, float* __restrict__ out)
{
    int i  = blockIdx.x * 256 + threadIdx.x;   // over N/4
    int w4 = i % (W / 4);
    int t  = i / (W / 4);
    int h  = t % H;  t /= H;
    int d  = t % D;  t /= D;
    int b  = t / C;                            // t = b*C + c

    const float4* f4  = (const float4*)fix;
    const float4* m4  = (const float4*)mov;
    const float4* gf4 = (const float4*)(ws + OFF_GF);
    const float4* gm4 = (const float4*)(ws + OFF_GM);
    float4*       o4  = (float4*)out;

    int sp = ((b * D + d) * H + h) * (W / 4) + w4;
    float4 f = f4[i], m = m4[i], gf = gf4[sp], gm = gm4[sp];

    float4 of, om;
    of.x = fmaf(m.x, gf.x, f.x); of.y = fmaf(m.y, gf.y, f.y);
    of.z = fmaf(m.z, gf.z, f.z); of.w = fmaf(m.w, gf.w, f.w);
    om.x = fmaf(f.x, gm.x, m.x); om.y = fmaf(f.y, gm.y, m.y);
    om.z = fmaf(f.z, gm.z, m.z); om.w = fmaf(f.w, gm.w, m.w);

    o4[i]         = of;
    o4[i + N / 4] = om;
}

extern "C" void kernel_launch(void* const* d_in, const int* in_sizes, int n_in,
                              void* d_out, int out_size, void* d_ws, size_t ws_size,
                              hipStream_t stream)
{
    const float* fix = (const float*)d_in[0];
    const float* mov = (const float*)d_in[1];
    const float* wf  = (const float*)d_in[2];   // w_f2m: gate from fix
    const float* wm  = (const float*)d_in[3];   // w_m2f: gate from move
    float* ws  = (float*)d_ws;
    float* out = (float*)d_out;

    int pool_blocks = (B * PP / 4 + 255) / 256;   // 1919
    pool_pad_kernel<<<pool_blocks, 256, 0, stream>>>(fix, mov, ws);

    dim3 cb(8, 8, 4), cg(3, 6, 2 * B * (D / 4));  // 16h x 32w x 4d tiles
    conv_gate_kernel<<<cg, cb, 0, stream>>>(ws, wf, wm, ws);

    apply_kernel<<<(N / 4) / 256, 256, 0, stream>>>(fix, mov, ws, out);
}

// Round 2
// 465.639 us; speedup vs baseline: 1.0367x; 1.0367x over previous
//
#include <hip/hip_runtime.h>
#include <stdint.h>

// Problem constants (from reference setup_inputs)
constexpr int B = 2, C = 16, D = 80, H = 96, W = 96;
constexpr int S  = D * H * W;        // 737280 spatial per batch
constexpr int N  = B * C * S;        // 23592960 elems per tensor
// Padded pooled layout: halo of 3 on d/h; w gets 4 left (alignment) + 12 right
constexpr int DP = D + 6;            // 86
constexpr int HP = H + 6;            // 102
constexpr int WP = 112;              // 4 + 96 + 12, multiple of 4 for float4 rows
constexpr int PP = DP * HP * WP;     // 982464 per channel per batch

// Workspace float offsets (all multiples of 4 -> float4 aligned)
constexpr int OFF_FMAX = 0;
constexpr int OFF_FAVG = B * PP;
constexpr int OFF_MMAX = 2 * B * PP;
constexpr int OFF_MAVG = 3 * B * PP;
constexpr int OFF_GF   = 4 * B * PP;
constexpr int OFF_GM   = OFF_GF + B * S;

// Conv tiling: block = 8h x 96w x 5d rolling; stages 16 padded rows x 112 w
constexpr int LD    = 5;                  // d outputs per block (80/5 = 16 chunks)
constexpr int TH    = 8;                  // h output rows per block
constexpr int SROWS = 16;                 // staged rows (14 needed; 16 -> 7168 B = 7x1024)
constexpr int CPLANE = SROWS * WP;        // 1792 floats per (c,plane) slab

__device__ __forceinline__ float sigmoidf_(float x) {
    return 1.0f / (1.0f + __expf(-x));
}

// async global->LDS, 16B per lane; LDS dest is wave-uniform base + lane*16
__device__ __forceinline__ void gload_lds16(const float* g, float* l) {
    __builtin_amdgcn_global_load_lds(
        (const __attribute__((address_space(1))) unsigned int*)g,
        (__attribute__((address_space(3))) unsigned int*)l,
        16, 0, 0);
}

// ---------------------------------------------------------------------------
// Kernel 1: channel max/mean pool of fix and move into zero-padded planar
// layout. One thread per PADDED float4 slot; halo lanes write zeros.
// ---------------------------------------------------------------------------
__global__ __launch_bounds__(256) void pool_pad_kernel(
    const float* __restrict__ fix, const float* __restrict__ mov,
    float* __restrict__ ws)
{
    int i = blockIdx.x * 256 + threadIdx.x;        // over B*PP/4 padded float4s
    if (i >= B * PP / 4) return;

    int wp4 = i % (WP / 4);                         // 0..27
    int t   = i / (WP / 4);
    int hp  = t % HP;  t /= HP;
    int dp  = t % DP;
    int b   = t / DP;

    float4* ws4 = (float4*)ws;
    bool interior = (dp >= 3) & (dp < 3 + D) & (hp >= 3) & (hp < 3 + H)
                  & (wp4 >= 1) & (wp4 < 25);

    if (!interior) {
        float4 z = make_float4(0.f, 0.f, 0.f, 0.f);
        ws4[0 * (B * PP / 4) + i] = z;
        ws4[1 * (B * PP / 4) + i] = z;
        ws4[2 * (B * PP / 4) + i] = z;
        ws4[3 * (B * PP / 4) + i] = z;
        return;
    }

    int d = dp - 3, h = hp - 3, w4 = wp4 - 1;
    const float4* f4 = (const float4*)fix;
    const float4* m4 = (const float4*)mov;
    int base = (b * C * S + (d * H + h) * W) / 4 + w4;   // channel 0 slot
    constexpr int cs = S / 4;                            // channel stride (f4)

    float4 v = f4[base];
    float4 fmx = v, fsm = v;
    #pragma unroll
    for (int c = 1; c < C; c++) {
        v = f4[base + c * cs];
        fmx.x = fmaxf(fmx.x, v.x); fmx.y = fmaxf(fmx.y, v.y);
        fmx.z = fmaxf(fmx.z, v.z); fmx.w = fmaxf(fmx.w, v.w);
        fsm.x += v.x; fsm.y += v.y; fsm.z += v.z; fsm.w += v.w;
    }
    v = m4[base];
    float4 mmx = v, msm = v;
    #pragma unroll
    for (int c = 1; c < C; c++) {
        v = m4[base + c * cs];
        mmx.x = fmaxf(mmx.x, v.x); mmx.y = fmaxf(mmx.y, v.y);
        mmx.z = fmaxf(mmx.z, v.z); mmx.w = fmaxf(mmx.w, v.w);
        msm.x += v.x; msm.y += v.y; msm.z += v.z; msm.w += v.w;
    }
    constexpr float inv = 1.0f / C;
    ws4[0 * (B * PP / 4) + i] = fmx;
    ws4[1 * (B * PP / 4) + i] = make_float4(fsm.x*inv, fsm.y*inv, fsm.z*inv, fsm.w*inv);
    ws4[2 * (B * PP / 4) + i] = mmx;
    ws4[3 * (B * PP / 4) + i] = make_float4(msm.x*inv, msm.y*inv, msm.z*inv, msm.w*inv);
}

// ---------------------------------------------------------------------------
// Kernel 2: d-rolling LDS-staged 7x7x7 conv + sigmoid.
// Block (192 thr = 24 w4 x 8 h) owns an 8h x 96w x 5d output tile.
// Streams 11 padded planes; per step stages next plane pair (2 c) into the
// spare LDS buffer via async global_load_lds (hidden under current compute),
// reads 7 rows (84 floats) once from LDS, and feeds up to 7 kd ring
// accumulators (static kd = 6-j after register shift). FMA count is exact
// (686/output); loads come from LDS instead of L2/HBM.
// ---------------------------------------------------------------------------
__global__ __launch_bounds__(192) void conv_roll_kernel(
    const float* __restrict__ ws_in,
    const float* __restrict__ w_f2m, const float* __restrict__ w_m2f,
    float* __restrict__ ws_out)
{
    __shared__ float lds[2][2][CPLANE];   // [parity][c][16*112] = 28672 B

    int bz     = blockIdx.z;              // 0..3
    int tensor = bz >> 1;
    int b      = bz & 1;
    int d0     = blockIdx.x * LD;         // 0..75
    int hb     = blockIdx.y * TH;         // output/padded row base 0..88

    const float* wsrc = tensor ? w_m2f : w_f2m;
    const float* pmax = ws_in + (tensor ? OFF_MMAX : OFF_FMAX) + b * PP;
    const float* pavg = ws_in + (tensor ? OFF_MAVG : OFF_FAVG) + b * PP;
    float*       gate = ws_out + (tensor ? OFF_GM : OFF_GF) + b * S;

    int tid  = threadIdx.x;               // 0..191
    int tw4  = tid % 24;                  // w float4 column
    int th   = tid / 24;                  // 0..7 output row in tile
    int wv   = tid >> 6;                  // wave 0..2
    int lane = tid & 63;

    // stage plane pair (padded plane dp) into buffer par: 14 chunks of 1024 B
    auto stage = [&](int dp, int par) {
        const float* s0 = pmax + dp * (HP * WP) + hb * WP;
        const float* s1 = pavg + dp * (HP * WP) + hb * WP;
        #pragma unroll
        for (int k = 0; k < 14; k++) {
            if ((k % 3) == wv) {
                int c = k / 7, ck = k % 7;
                gload_lds16((c ? s1 : s0) + ck * 256 + lane * 4,
                            &lds[par][c][ck * 256]);
            }
        }
    };

    float acc[7][4];
    #pragma unroll
    for (int j = 0; j < 7; j++)
        #pragma unroll
        for (int q = 0; q < 4; q++) acc[j][q] = 0.0f;

    stage(d0, 0);
    __syncthreads();                      // drains vmcnt -> buf0 ready

    #pragma unroll 1
    for (int s = 0; s < 11; s++) {
        int par = s & 1;
        if (s < 10) stage(d0 + s + 1, par ^ 1);   // hidden under this step's FMAs

        if (s <= 4) {                     // new output d0+s enters at ring slot 6
            acc[6][0] = 0.f; acc[6][1] = 0.f; acc[6][2] = 0.f; acc[6][3] = 0.f;
        }

        #pragma unroll
        for (int c = 0; c < 2; c++) {
            // read the 7 rows this thread needs, once per channel plane
            float row[7][12];
            #pragma unroll
            for (int kh = 0; kh < 7; kh++) {
                const float4* rp =
                    (const float4*)&lds[par][c][(th + kh) * WP + tw4 * 4];
                float4 a0 = rp[0], a1 = rp[1], a2 = rp[2];
                row[kh][0] = a0.x; row[kh][1]  = a0.y; row[kh][2]  = a0.z; row[kh][3]  = a0.w;
                row[kh][4] = a1.x; row[kh][5]  = a1.y; row[kh][6]  = a1.z; row[kh][7]  = a1.w;
                row[kh][8] = a2.x; row[kh][9]  = a2.y; row[kh][10] = a2.z; row[kh][11] = a2.w;
            }
            // ring slot j holds output d = d0+s-6+j; its kd for this plane is 6-j
            #pragma unroll
            for (int j = 0; j < 7; j++) {
                if (s >= 6 - j && s <= 10 - j) {      // wave-uniform validity
                    float wt[49];                     // wave-uniform -> SGPRs
                    #pragma unroll
                    for (int t = 0; t < 49; t++)
                        wt[t] = wsrc[(c * 7 + (6 - j)) * 49 + t];
                    #pragma unroll
                    for (int kh = 0; kh < 7; kh++) {
                        #pragma unroll
                        for (int kw = 0; kw < 7; kw++) {
                            float wvv = wt[kh * 7 + kw];
                            #pragma unroll
                            for (int ow = 0; ow < 4; ow++)
                                acc[j][ow] = fmaf(row[kh][1 + kw + ow], wvv, acc[j][ow]);
                        }
                    }
                }
            }
        }

        if (s >= 6) {                      // ring slot 0 (oldest) is complete
            int dd = d0 + s - 6;
            float4 o;
            o.x = sigmoidf_(acc[0][0]);
            o.y = sigmoidf_(acc[0][1]);
            o.z = sigmoidf_(acc[0][2]);
            o.w = sigmoidf_(acc[0][3]);
            *(float4*)(gate + (dd * H + hb + th) * W + tw4 * 4) = o;
        }

        // shift ring: slot j <- j+1 (static register moves)
        #pragma unroll
        for (int j = 0; j < 6; j++)
            #pragma unroll
            for (int q = 0; q < 4; q++) acc[j][q] = acc[j + 1][q];

        __syncthreads();                   // staged plane ready; readers retired
    }
}

// ---------------------------------------------------------------------------
// Kernel 3: elementwise cross-apply, full-occupancy streaming.
// fix_out = move*g_fix + fix ; move_out = fix*g_move + move.
// ---------------------------------------------------------------------------
__global__ __launch_bounds__(256) void apply_kernel(
    const float* __restrict__ fix, const float* __restrict__ mov,
    const float* __restrict__ ws, float* __restrict__ out)
{
    int i  = blockIdx.x * 256 + threadIdx.x;   // over N/4
    int w4 = i % (W / 4);
    int t  = i / (W / 4);
    int h  = t % H;  t /= H;
    int d  = t % D;  t /= D;
    int b  = t / C;                            // t = b*C + c

    const float4* f4  = (const float4*)fix;
    const float4* m4  = (const float4*)mov;
    const float4* gf4 = (const float4*)(ws + OFF_GF);
    const float4* gm4 = (const float4*)(ws + OFF_GM);
    float4*       o4  = (float4*)out;

    int sp = ((b * D + d) * H + h) * (W / 4) + w4;
    float4 f = f4[i], m = m4[i], gf = gf4[sp], gm = gm4[sp];

    float4 of, om;
    of.x = fmaf(m.x, gf.x, f.x); of.y = fmaf(m.y, gf.y, f.y);
    of.z = fmaf(m.z, gf.z, f.z); of.w = fmaf(m.w, gf.w, f.w);
    om.x = fmaf(f.x, gm.x, m.x); om.y = fmaf(f.y, gm.y, m.y);
    om.z = fmaf(f.z, gm.z, m.z); om.w = fmaf(f.w, gm.w, m.w);

    o4[i]         = of;
    o4[i + N / 4] = om;
}

extern "C" void kernel_launch(void* const* d_in, const int* in_sizes, int n_in,
                              void* d_out, int out_size, void* d_ws, size_t ws_size,
                              hipStream_t stream)
{
    const float* fix = (const float*)d_in[0];
    const float* mov = (const float*)d_in[1];
    const float* wf  = (const float*)d_in[2];   // w_f2m: gate from fix
    const float* wm  = (const float*)d_in[3];   // w_m2f: gate from move
    float* ws  = (float*)d_ws;
    float* out = (float*)d_out;

    int pool_blocks = (B * PP / 4 + 255) / 256;   // 1919
    pool_pad_kernel<<<pool_blocks, 256, 0, stream>>>(fix, mov, ws);

    dim3 cg(D / LD, H / TH, 2 * B);               // (16, 12, 4) = 768 blocks
    conv_roll_kernel<<<cg, 192, 0, stream>>>(ws, wf, wm, ws);

    apply_kernel<<<(N / 4) / 256, 256, 0, stream>>>(fix, mov, ws, out);
}